// Round 1
// baseline (458.562 us; speedup 1.0000x reference)
//
#include <hip/hip_runtime.h>
#include <hip/hip_bf16.h>

// Edge-parallel kernel: one thread per edge, gather node data, scatter atomics.
__global__ void __launch_bounds__(256)
conduction_edge_kernel(const float* __restrict__ T,
                       const float* __restrict__ cp,
                       const float* __restrict__ L,
                       const float* __restrict__ cond,
                       const float* __restrict__ A,
                       const float* __restrict__ time_step,
                       const int* __restrict__ src,
                       const int* __restrict__ dst,
                       float* __restrict__ out,
                       int n_edges) {
    int i = blockIdx.x * blockDim.x + threadIdx.x;
    if (i >= n_edges) return;

    const float dt = time_step[0];          // scalar, L2-cached broadcast

    const int s = src[i];
    const int d = dst[i];

    const float Ts = T[s];
    const float Td = T[d];
    float delta = Ts - Td;                  // relu(T_src - T_dst)
    delta = delta > 0.0f ? delta : 0.0f;

    // If delta == 0, E_transf = min(0, 0) = 0 -> skip both atomics (~50% of edges).
    if (delta <= 0.0f) return;

    const float g  = delta / L[i];
    const float x  = g * cond[i];           // >= 0 by construction
    const float hfd = x > 0.0f ? cbrtf(x) : 0.0f;
    const float e_cond = hfd * A[i] * dt;

    const float cs = cp[s];
    const float cd = cp[d];
    const float comb = (cd * cs) / (cd + cs);
    const float max_e = delta * comb;

    const float Et = fminf(e_cond, max_e);

    atomicAdd(&out[d],  Et);   // heat_received
    atomicAdd(&out[s], -Et);   // heat_sent
}

extern "C" void kernel_launch(void* const* d_in, const int* in_sizes, int n_in,
                              void* d_out, int out_size, void* d_ws, size_t ws_size,
                              hipStream_t stream) {
    const float* T    = (const float*)d_in[0];
    const float* cp   = (const float*)d_in[1];
    const float* L    = (const float*)d_in[2];
    const float* cond = (const float*)d_in[3];
    const float* A    = (const float*)d_in[4];
    const float* ts   = (const float*)d_in[5];
    const int*   src  = (const int*)d_in[6];
    const int*   dst  = (const int*)d_in[7];
    float* out = (float*)d_out;

    const int n_edges = in_sizes[2];        // L is per-edge

    // Harness poisons d_out to 0xAA before every launch; zero it (capture-safe).
    hipMemsetAsync(out, 0, (size_t)out_size * sizeof(float), stream);

    const int block = 256;
    const int grid = (n_edges + block - 1) / block;
    conduction_edge_kernel<<<grid, block, 0, stream>>>(
        T, cp, L, cond, A, ts, src, dst, out, n_edges);
}

// Round 2
// 441.408 us; speedup vs baseline: 1.0389x; 1.0389x over previous
//
#include <hip/hip_runtime.h>
#include <hip/hip_bf16.h>

#define N_COPIES 8

// Pack (T, cp) per node into float2 so each edge endpoint is ONE random 8B
// load (one cacheline) instead of two 4B loads to two different lines.
__global__ void __launch_bounds__(256)
pack_nodes_kernel(const float* __restrict__ T, const float* __restrict__ cp,
                  float2* __restrict__ nodes, int n) {
    int i = blockIdx.x * blockDim.x + threadIdx.x;
    if (i < n) nodes[i] = make_float2(T[i], cp[i]);
}

// Edge-parallel: gather packed node data, scatter atomics into one of
// N_COPIES replicated accumulators (blockIdx%8 ~ XCD round-robin) to cut
// per-address contention 8x.
__global__ void __launch_bounds__(256)
conduction_edge_kernel(const float2* __restrict__ nodes,
                       const float* __restrict__ L,
                       const float* __restrict__ cond,
                       const float* __restrict__ A,
                       const float* __restrict__ time_step,
                       const int* __restrict__ src,
                       const int* __restrict__ dst,
                       float* __restrict__ copies,   // [N_COPIES][n_nodes]
                       int n_nodes, int n_edges) {
    int i = blockIdx.x * blockDim.x + threadIdx.x;
    if (i >= n_edges) return;

    float* __restrict__ acc = copies + (size_t)(blockIdx.x & (N_COPIES - 1)) * n_nodes;

    const int s = src[i];
    const int d = dst[i];

    const float2 ns = nodes[s];
    const float2 nd = nodes[d];
    float delta = ns.x - nd.x;              // relu(T_src - T_dst)
    if (delta <= 0.0f) return;              // E_transf == 0 exactly -> skip atomics

    const float dt = time_step[0];
    const float g  = delta / L[i];
    const float x  = g * cond[i];
    const float hfd = cbrtf(x);             // x > 0 here
    const float e_cond = hfd * A[i] * dt;

    const float comb = (nd.y * ns.y) / (nd.y + ns.y);
    const float max_e = delta * comb;

    const float Et = fminf(e_cond, max_e);

    atomicAdd(&acc[d],  Et);   // heat_received
    atomicAdd(&acc[s], -Et);   // heat_sent
}

// Sum the replicated accumulators into the output (also writes zeros where
// nothing accumulated, so no memset of d_out is needed).
__global__ void __launch_bounds__(256)
reduce_copies_kernel(const float* __restrict__ copies, float* __restrict__ out,
                     int n_nodes) {
    int i = blockIdx.x * blockDim.x + threadIdx.x;
    if (i >= n_nodes) return;
    float v = 0.0f;
#pragma unroll
    for (int r = 0; r < N_COPIES; ++r)
        v += copies[(size_t)r * n_nodes + i];
    out[i] = v;
}

// Fallback (ws too small): original direct-atomic kernel.
__global__ void __launch_bounds__(256)
conduction_edge_direct(const float* __restrict__ T, const float* __restrict__ cp,
                       const float* __restrict__ L, const float* __restrict__ cond,
                       const float* __restrict__ A, const float* __restrict__ time_step,
                       const int* __restrict__ src, const int* __restrict__ dst,
                       float* __restrict__ out, int n_edges) {
    int i = blockIdx.x * blockDim.x + threadIdx.x;
    if (i >= n_edges) return;
    const int s = src[i], d = dst[i];
    float delta = T[s] - T[d];
    if (delta <= 0.0f) return;
    const float dt = time_step[0];
    const float x = (delta / L[i]) * cond[i];
    const float e_cond = cbrtf(x) * A[i] * dt;
    const float cs = cp[s], cd = cp[d];
    const float max_e = delta * (cd * cs) / (cd + cs);
    const float Et = fminf(e_cond, max_e);
    atomicAdd(&out[d],  Et);
    atomicAdd(&out[s], -Et);
}

extern "C" void kernel_launch(void* const* d_in, const int* in_sizes, int n_in,
                              void* d_out, int out_size, void* d_ws, size_t ws_size,
                              hipStream_t stream) {
    const float* T    = (const float*)d_in[0];
    const float* cp   = (const float*)d_in[1];
    const float* L    = (const float*)d_in[2];
    const float* cond = (const float*)d_in[3];
    const float* A    = (const float*)d_in[4];
    const float* ts   = (const float*)d_in[5];
    const int*   src  = (const int*)d_in[6];
    const int*   dst  = (const int*)d_in[7];
    float* out = (float*)d_out;

    const int n_nodes = in_sizes[0];
    const int n_edges = in_sizes[2];

    const int block = 256;
    const int egrid = (n_edges + block - 1) / block;
    const int ngrid = (n_nodes + block - 1) / block;

    const size_t nodes_bytes  = (size_t)n_nodes * sizeof(float2);
    const size_t copies_bytes = (size_t)N_COPIES * n_nodes * sizeof(float);

    if (ws_size >= nodes_bytes + copies_bytes) {
        float2* nodes  = (float2*)d_ws;
        float*  copies = (float*)((char*)d_ws + nodes_bytes);

        // Zero the replicated accumulators (ws is poisoned to 0xAA each call).
        hipMemsetAsync(copies, 0, copies_bytes, stream);
        pack_nodes_kernel<<<ngrid, block, 0, stream>>>(T, cp, nodes, n_nodes);
        conduction_edge_kernel<<<egrid, block, 0, stream>>>(
            nodes, L, cond, A, ts, src, dst, copies, n_nodes, n_edges);
        reduce_copies_kernel<<<ngrid, block, 0, stream>>>(copies, out, n_nodes);
    } else {
        hipMemsetAsync(out, 0, (size_t)out_size * sizeof(float), stream);
        conduction_edge_direct<<<egrid, block, 0, stream>>>(
            T, cp, L, cond, A, ts, src, dst, out, n_edges);
    }
}